// Round 9
// baseline (1303.186 us; speedup 1.0000x reference)
//
#include <hip/hip_runtime.h>
#include <hip/hip_bf16.h>
#include <cstdint>

typedef __bf16 bf16x8 __attribute__((ext_vector_type(8)));
typedef float  f32x4  __attribute__((ext_vector_type(4)));

// ---------------- workspace layout (bytes) ----------------
constexpr size_t WTP_OFF  = 0;         // [24][256][192] bf16 prolog W^T
constexpr size_t WTHH_OFF = 2359296;   // [24][192][64]  bf16 W_hh^T per node
constexpr size_t WTFC_OFF = 2949120;   // [24][64][64]   bf16 W_fc^T per node
constexpr size_t GN_OFF   = 3145728;   // [4][24][24] f32 row-L1-normalized
constexpr size_t BGI_OFF  = 3154944;   // [24][192] f32 folded gi bias
constexpr size_t BHN2_OFF = 3173376;   // [64 j][24 n] f32 b_hh n-slice, n-contig
constexpr size_t BFC2_OFF = 3179520;   // [64 o][24 n] f32 b_fc, n-contig
constexpr size_t TWS_OFF  = 3185664;   // [2048][24][256] bf16 prolog GEMM result
constexpr size_t GIWS_OFF = 28351488;  // [2048][192][24] bf16 gi (n innermost)
constexpr size_t H0WS_OFF = 47225856;  // [2048][24][64] bf16 h0
constexpr size_t WS_NEED  = 53517312;

// t_l (R2-verified): [512 c][8 octet][8 mm] ushort, 64 KB; 4 octets/row used.
#define BLK(c,q) ((((q) ^ ((c)&3)) | ((((c)>>2)&1)<<2)))
// h_l (ushort index): [n][b][i], b in [0,8), i XOR-swizzled by b and n (R2-verified)
#define HL(n,b,i) ((((n)*8+(b))<<6) + ((i) ^ (((b)&7)<<3) ^ ((((n)>>2)&3)<<4)))

__device__ __forceinline__ float bf2f(ushort u){
  union { uint32_t i; float f; } v; v.i = ((uint32_t)u) << 16; return v.f;
}
__device__ __forceinline__ ushort f2bf(float f){
  union { float f; uint32_t i; } v; v.f = f;
  return (ushort)((v.i + 0x7fffu + ((v.i >> 16) & 1u)) >> 16);
}
__device__ __forceinline__ f32x4 mfma16(bf16x8 a, bf16x8 b, f32x4 c){
  return __builtin_amdgcn_mfma_f32_16x16x32_bf16(a, b, c, 0, 0, 0);
}
__device__ __forceinline__ float sigmoidf_(float x){
  float e = __expf(-x); return __builtin_amdgcn_rcpf(1.f + e);
}
__device__ __forceinline__ float tanhf_(float x){
  float e = __expf(-2.f*fabsf(x));
  float r = (1.f - e)*__builtin_amdgcn_rcpf(1.f + e);
  return copysignf(r, x);
}

// ---------------- G row-normalize ----------------
__global__ void k_gnorm(const float* g0, const float* g1, const float* g2, const float* g3, float* gn){
  int t = threadIdx.x;
  if (t >= 96) return;
  int mat = t / 24, row = t % 24;
  const float* G = (mat==0)? g0 : (mat==1)? g1 : (mat==2)? g2 : g3;
  float s = 0.f;
  for (int m=0;m<24;m++) s += fabsf(G[row*24+m]);
  float inv = 1.f/s;
  for (int m=0;m<24;m++) gn[mat*576 + row*24 + m] = G[row*24+m]*inv;
}

// ---------------- weight transpose/cast + bias prep ----------------
__global__ void k_prep(const float* Wih, const float* Winit, const float* Whh, const float* Wfc,
                       const float* bih, const float* bhh, const float* bfc,
                       ushort* wtp, ushort* wthh, ushort* wtfc, float* bgi,
                       float* bhn2, float* bfc2){
  int stride = gridDim.x*blockDim.x;
  int t0 = blockIdx.x*blockDim.x + threadIdx.x;
  for (int f = t0; f < 884736; f += stride){
    int m = f/36864, rr = f - m*36864, o = rr/192, i = rr - o*192;
    wtp[((size_t)m*256 + o)*192 + i] = f2bf(Wih[(size_t)m*36864 + i*192 + o]);
  }
  for (int f = t0; f < 294912; f += stride){
    int m = f/12288, rr = f - m*12288, o = rr/192, i = rr - o*192;
    wtp[((size_t)m*256 + 192 + o)*192 + i] = f2bf(Winit[(size_t)m*12288 + i*64 + o]);
  }
  for (int f = t0; f < 294912; f += stride){
    int m = f/12288, rr = f - m*12288, o = rr/64, i = rr - o*64;
    wthh[((size_t)m*192 + o)*64 + i] = f2bf(Whh[(size_t)m*12288 + i*192 + o]);
  }
  for (int f = t0; f < 98304; f += stride){
    int m = f/4096, rr = f - m*4096, o = rr/64, i = rr - o*64;
    wtfc[((size_t)m*64 + o)*64 + i] = f2bf(Wfc[(size_t)m*4096 + i*64 + o]);
  }
  for (int f = t0; f < 4608; f += stride){
    int o = f % 192;
    bgi[f] = bih[f] + ((o<128) ? bhh[f] : 0.f);
  }
  for (int f = t0; f < 1536; f += stride){
    int o = f/24, n = f - o*24;
    bhn2[f] = bhh[n*192 + 128 + o];
    bfc2[f] = bfc[n*64 + o];
  }
}

// ---------------- prolog per-node GEMM: rec(64b x 192) @ W^T -> t_ws ----------------
__global__ __launch_bounds__(256) void k_p1(const float* x, const float* h, const ushort* wtp,
                                            ushort* t_ws, int tsel, int o_base, int ntt){
  __shared__ ushort A_lds[64*192];
  int tid = threadIdx.x, w = tid>>6, l = tid&63;
  int m = blockIdx.x, b0 = blockIdx.y*64;
  for (int f = tid; f < 64*192; f += 256){
    int b = f/192, i = f - b*192;
    float v = (i < 64) ? x[((size_t)(b0+b)*3 + tsel)*1536 + m*64 + i]
                       : h[((size_t)(b0+b)*24 + m)*128 + (i-64)];
    A_lds[b*192 + (i ^ ((b&7)<<3))] = f2bf(v);
  }
  __syncthreads();
  for (int mt=0; mt<4; mt++){
    for (int nt = w; nt < ntt; nt += 4){
      f32x4 acc = {0.f,0.f,0.f,0.f};
      int rowb = mt*16 + (l&15);
      int og = o_base + nt*16 + (l&15);
      #pragma unroll
      for (int kc=0;kc<6;kc++){
        int i0 = kc*32 + ((l>>4)<<3);
        bf16x8 av = __builtin_bit_cast(bf16x8, *(const uint4*)(A_lds + rowb*192 + (i0 ^ ((rowb&7)<<3))));
        bf16x8 bv = __builtin_bit_cast(bf16x8, *(const uint4*)(wtp + ((size_t)m*256 + og)*192 + i0));
        acc = mfma16(av, bv, acc);
      }
      #pragma unroll
      for (int r=0;r<4;r++){
        int bp = mt*16 + ((l>>4)<<2) + r;
        t_ws[((size_t)(b0+bp)*24 + m)*256 + og] = f2bf(acc[r]);
      }
    }
  }
}

// ---------------- prolog mix: gi = Gn_ih @ t + bias ; h0 = Gn_init @ t + b_init ----------------
__global__ __launch_bounds__(256) void k_p2(const ushort* t_ws, const float* gn, const float* bgi,
                                            const float* binit, ushort* gi_ws, ushort* h0_ws){
  __shared__ ushort t_l[24*256];
  int tid = threadIdx.x; size_t b = blockIdx.x;
  const uint4* src = (const uint4*)(t_ws + b*6144);
  uint4* dst = (uint4*)t_l;
  for (int f = tid; f < 768; f += 256) dst[f] = src[f];
  __syncthreads();
  int o = tid;
  float acc[24];
  if (o < 192){
    const float* gih = gn + 576;
    #pragma unroll
    for (int n=0;n<24;n++) acc[n] = bgi[n*192+o];
    for (int m=0;m<24;m++){
      float tv = bf2f(t_l[m*256+o]);
      #pragma unroll
      for (int n=0;n<24;n++) acc[n] = fmaf(gih[n*24+m], tv, acc[n]);
    }
    uint ov[12];
    #pragma unroll
    for (int q=0;q<12;q++) ov[q] = (uint)f2bf(acc[2*q]) | ((uint)f2bf(acc[2*q+1])<<16);
    uint4* gdst = (uint4*)(gi_ws + (b*192 + o)*24);
    gdst[0] = make_uint4(ov[0],ov[1],ov[2],ov[3]);
    gdst[1] = make_uint4(ov[4],ov[5],ov[6],ov[7]);
    gdst[2] = make_uint4(ov[8],ov[9],ov[10],ov[11]);
  } else {
    int o2 = o - 192;
    const float* gin = gn;
    #pragma unroll
    for (int n=0;n<24;n++) acc[n] = binit[n*64+o2];
    for (int m=0;m<24;m++){
      float tv = bf2f(t_l[m*256 + 192 + o2]);
      #pragma unroll
      for (int n=0;n<24;n++) acc[n] = fmaf(gin[n*24+m], tv, acc[n]);
    }
    #pragma unroll
    for (int n=0;n<24;n++) h0_ws[(b*24+n)*64 + o2] = f2bf(acc[n]);
  }
}

// ---------------- x_t passthrough (NT stores) ----------------
__global__ void k_copy(const f32x4* x, f32x4* out2){
  int i = blockIdx.x*blockDim.x + threadIdx.x;
  for (; i < 2048*384; i += gridDim.x*blockDim.x){
    int b = i/384; int r = i - b*384;
    f32x4 v = x[(size_t)b*1152 + 768 + r];
    __builtin_nontemporal_store(v, &out2[i]);
  }
}

// ---------------- main GRU loop: 256 blocks x 8-batch tile, 8 waves ----------------
// Register-prefetched weights: each t-GEMM phase is global-load-free; prefetch for
// phase p+1 issues at the start of mix phase p (covered by mix MFMA+VALU work).
__global__ __launch_bounds__(512,1) void k_main(const ushort* giws, const ushort* h0ws,
    const ushort* wthh, const ushort* wtfc, const float* gn,
    const float* bhn2, const float* bfc2, float* out){
  __shared__ ushort h_l[12288];   // 24n x 8b x 64i, swizzled (24.6 KB)
  __shared__ ushort t_l[32768];   // 512c x 64 (64 KB), BLK octet layout
  __shared__ float bhn_l[1568];   // [o][n], zero-padded tail
  __shared__ float bfc_l[1568];
  const int tid = threadIdx.x, w = tid>>6, l = tid&63;
  const int lr = l&15, lq = l>>4;
  const int b0 = blockIdx.x*8;

  for (int f = tid; f < 1568; f += 512){
    bhn_l[f] = (f < 1536) ? bhn2[f] : 0.f;
    bfc_l[f] = (f < 1536) ? bfc2[f] : 0.f;
  }
  for (int f = tid; f < 4096; f += 512){
    int c = f>>3, mm = f&7;
    t_l[(c<<6) + (BLK(c,3)<<3) + mm] = 0;
  }
  for (int f = tid; f < 3072; f += 512){
    int idx = f<<2; int b = idx/1536; int r2 = idx - b*1536; int n = r2>>6; int i = r2&63;
    ushort4 v = *(const ushort4*)(h0ws + (size_t)(b0+b)*1536 + r2);
    *(ushort4*)(h_l + HL(n,b,i)) = v;
  }
  // constant Gn A-fragments (rows n, k=m, zero-padded)
  bf16x8 gnhh[2], gnfc[2];
  #pragma unroll
  for (int nt2=0; nt2<2; nt2++){
    union { ushort s[8]; bf16x8 v; } uh, uf;
    int row = nt2*16 + lr;
    #pragma unroll
    for (int jj=0;jj<8;jj++){
      int m = lq*8 + jj;
      bool ok = (row<24) && (m<24);
      uh.s[jj] = ok ? f2bf(gn[2*576 + row*24 + m]) : (ushort)0;
      uf.s[jj] = ok ? f2bf(gn[3*576 + row*24 + m]) : (ushort)0;
    }
    gnhh[nt2] = uh.v; gnfc[nt2] = uf.v;
  }
  // per-task mix coordinates + step-invariant gi fragments in regs
  int cb[8], co[8], cn0[8];
  ushort4 gih0[8], gih1[8], gih2[8];
  #pragma unroll
  for (int k=0;k<8;k++){
    int tId = w + k*8, ct = tId>>1, nt2 = tId&1;
    int c = ct*16 + lr;
    cb[k] = c>>6; co[k] = c&63; cn0[k] = nt2*16 + lq*4;
    size_t base = ((size_t)(b0+cb[k])*192 + co[k])*24 + cn0[k];
    gih0[k] = *(const ushort4*)(giws + base);            // r  (slice 0)
    gih1[k] = *(const ushort4*)(giws + base + 64*24);    // u  (slice 1)
    gih2[k] = *(const ushort4*)(giws + base + 128*24);   // n  (slice 2)
  }

  // full next-phase weight prefetch (24 x uint4 = 96 VGPR)
  uint4 wpre[24];
  auto pre_hh = [&](int gsw){
    #pragma unroll
    for (int k=0;k<12;k++){
      int tId = w + k*8, m = tId>>2, nt = tId&3;
      int o = nt*16 + lr;
      const ushort* wb = wthh + (((size_t)m*192 + gsw*64 + o)<<6);
      wpre[2*k]   = *(const uint4*)(wb + lq*8);
      wpre[2*k+1] = *(const uint4*)(wb + 32 + lq*8);
    }
  };
  auto pre_fc = [&](){
    #pragma unroll
    for (int k=0;k<12;k++){
      int tId = w + k*8, m = tId>>2, nt = tId&3;
      int o = nt*16 + lr;
      const ushort* wb = wtfc + ((((size_t)m<<6) + o)<<6);
      wpre[2*k]   = *(const uint4*)(wb + lq*8);
      wpre[2*k+1] = *(const uint4*)(wb + 32 + lq*8);
    }
  };

  __syncthreads();
  pre_hh(0);                       // prime gate-0 weights
  asm volatile("" ::: "memory");

  float g1[8][4];   // r-gate, then nn
  for (int step=0; step<16; step++){
    // phases: p=0 -> r (W cols 0-63), p=1 -> n (cols 128-191), p=2 -> u (cols 64-127)
    #pragma unroll 1
    for (int p=0; p<3; p++){
      __syncthreads();             // drains the prefetch issued last phase
      // per-node t-GEMM (12 tasks/wave), weights from registers — NO global loads
      #pragma unroll
      for (int k=0;k<12;k++){
        int tId = w + k*8, m = tId>>2, nt = tId&3;
        int o_loc = nt*16 + lr;
        bf16x8 av0 = __builtin_bit_cast(bf16x8, *(const uint4*)(h_l + HL(m, lr&7, lq*8)));
        f32x4 acc = mfma16(av0, __builtin_bit_cast(bf16x8, wpre[2*k]), (f32x4){0.f,0.f,0.f,0.f});
        bf16x8 av1 = __builtin_bit_cast(bf16x8, *(const uint4*)(h_l + HL(m, lr&7, 32 + lq*8)));
        acc = mfma16(av1, __builtin_bit_cast(bf16x8, wpre[2*k+1]), acc);
        if (l < 32){
          #pragma unroll
          for (int r=0;r<4;r++){
            int bp = lq*4 + r, c = (bp<<6) + o_loc;
            t_l[(c<<6) + (BLK(c, m>>3)<<3) + (m&7)] = f2bf(acc[r]);
          }
        }
      }
      __syncthreads();
      // prefetch next phase's weights (covered by the mix work below)
      if (p==0)      pre_hh(2);
      else if (p==1) pre_hh(1);
      else           pre_fc();
      asm volatile("" ::: "memory");
      // node mix (8 tasks/wave) + gate math
      #pragma unroll
      for (int k=0;k<8;k++){
        int tId = w + k*8, nt2 = tId&1;
        int c = (tId>>1)*16 + lr;
        f32x4 cin;
        if (p==1){
          cin = *(const f32x4*)(bhn_l + co[k]*24 + cn0[k]);
        } else {
          ushort4 gp = (p==0) ? gih0[k] : gih1[k];
          cin[0]=bf2f(gp.x); cin[1]=bf2f(gp.y); cin[2]=bf2f(gp.z); cin[3]=bf2f(gp.w);
        }
        bf16x8 bv = __builtin_bit_cast(bf16x8, *(const uint4*)(t_l + (c<<6) + (BLK(c,lq)<<3)));
        f32x4 fa = mfma16(gnhh[nt2], bv, cin);
        if (p==0){
          #pragma unroll
          for (int r=0;r<4;r++) g1[k][r] = sigmoidf_(fa[r]);
        } else if (p==1){
          ushort4 gp = gih2[k];
          float gin[4] = { bf2f(gp.x), bf2f(gp.y), bf2f(gp.z), bf2f(gp.w) };
          #pragma unroll
          for (int r=0;r<4;r++) g1[k][r] = tanhf_(gin[r] + g1[k][r]*fa[r]);
        } else {
          #pragma unroll
          for (int r=0;r<4;r++){
            int n = cn0[k] + r;
            if (n < 24){
              float ug = sigmoidf_(fa[r]);
              float hp = bf2f(h_l[HL(n, cb[k], co[k])]);
              float hv = (1.f-ug)*g1[k][r] + ug*hp;
              h_l[HL(n, cb[k], co[k])] = f2bf(hv);
            }
          }
        }
      }
    }
    __syncthreads();
    // fc t2-GEMM (12 tasks/wave), weights from registers
    #pragma unroll
    for (int k=0;k<12;k++){
      int tId = w + k*8, m = tId>>2, nt = tId&3;
      int o_loc = nt*16 + lr;
      bf16x8 av0 = __builtin_bit_cast(bf16x8, *(const uint4*)(h_l + HL(m, lr&7, lq*8)));
      f32x4 acc = mfma16(av0, __builtin_bit_cast(bf16x8, wpre[2*k]), (f32x4){0.f,0.f,0.f,0.f});
      bf16x8 av1 = __builtin_bit_cast(bf16x8, *(const uint4*)(h_l + HL(m, lr&7, 32 + lq*8)));
      acc = mfma16(av1, __builtin_bit_cast(bf16x8, wpre[2*k+1]), acc);
      if (l < 32){
        #pragma unroll
        for (int r=0;r<4;r++){
          int bp = lq*4 + r, c = (bp<<6) + o_loc;
          t_l[(c<<6) + (BLK(c, m>>3)<<3) + (m&7)] = f2bf(acc[r]);
        }
      }
    }
    __syncthreads();
    // prefetch next step's gate-0 weights, then fc mix + tanh + NT store
    pre_hh(0);
    asm volatile("" ::: "memory");
    #pragma unroll
    for (int k=0;k<8;k++){
      int tId = w + k*8, nt2 = tId&1;
      int c = (tId>>1)*16 + lr;
      f32x4 cin = *(const f32x4*)(bfc_l + co[k]*24 + cn0[k]);
      bf16x8 bv = __builtin_bit_cast(bf16x8, *(const uint4*)(t_l + (c<<6) + (BLK(c,lq)<<3)));
      f32x4 fa = mfma16(gnfc[nt2], bv, cin);
      #pragma unroll
      for (int r=0;r<4;r++){
        int n = cn0[k] + r;
        if (n < 24){
          float y = tanhf_(fa[r]);
          __builtin_nontemporal_store(y,
            &out[((size_t)(b0+cb[k])*16 + step)*1536 + (n<<6) + co[k]]);
        }
      }
    }
  }
}

extern "C" void kernel_launch(void* const* d_in, const int* in_sizes, int n_in,
                              void* d_out, int out_size, void* d_ws, size_t ws_size,
                              hipStream_t stream){
  if (ws_size < WS_NEED) return;
  const float* x     = (const float*)d_in[0];
  const float* h     = (const float*)d_in[1];
  const float* Winit = (const float*)d_in[4];
  const float* binit = (const float*)d_in[5];
  const float* Ginit = (const float*)d_in[6];
  const float* Wih   = (const float*)d_in[7];
  const float* bih   = (const float*)d_in[8];
  const float* Gih   = (const float*)d_in[9];
  const float* Whh   = (const float*)d_in[10];
  const float* bhh   = (const float*)d_in[11];
  const float* Ghh   = (const float*)d_in[12];
  const float* Wfc   = (const float*)d_in[13];
  const float* bfc   = (const float*)d_in[14];
  const float* Gfc   = (const float*)d_in[15];
  char* ws = (char*)d_ws;
  ushort* wtp  = (ushort*)(ws + WTP_OFF);
  ushort* wthh = (ushort*)(ws + WTHH_OFF);
  ushort* wtfc = (ushort*)(ws + WTFC_OFF);
  float*  gn   = (float*)(ws + GN_OFF);
  float*  bgi  = (float*)(ws + BGI_OFF);
  float*  bhn2 = (float*)(ws + BHN2_OFF);
  float*  bfc2 = (float*)(ws + BFC2_OFF);
  ushort* tws  = (ushort*)(ws + TWS_OFF);
  ushort* giws = (ushort*)(ws + GIWS_OFF);
  ushort* h0ws = (ushort*)(ws + H0WS_OFF);
  float* out  = (float*)d_out;
  float* out2 = out + (size_t)2048*16*1536;

  k_gnorm<<<1, 128, 0, stream>>>(Ginit, Gih, Ghh, Gfc, gn);
  k_prep<<<512, 256, 0, stream>>>(Wih, Winit, Whh, Wfc, bih, bhh, bfc, wtp, wthh, wtfc, bgi, bhn2, bfc2);
  k_p1<<<dim3(24,32), 256, 0, stream>>>(x, h, wtp, tws, 2, 0, 12);
  k_p1<<<dim3(24,32), 256, 0, stream>>>(x, h, wtp, tws, 1, 192, 4);
  k_p2<<<2048, 256, 0, stream>>>(tws, gn, bgi, binit, giws, h0ws);
  k_copy<<<2048, 256, 0, stream>>>((const f32x4*)x, (f32x4*)out2);
  k_main<<<256, 512, 0, stream>>>(giws, h0ws, wthh, wtfc, gn, bhn2, bfc2, out);
}

// Round 10
// 585.147 us; speedup vs baseline: 2.2271x; 2.2271x over previous
//
#include <hip/hip_runtime.h>
#include <hip/hip_bf16.h>
#include <cstdint>

typedef __bf16 bf16x8 __attribute__((ext_vector_type(8)));
typedef float  f32x4  __attribute__((ext_vector_type(4)));

// ---------------- workspace layout (bytes) ----------------
constexpr size_t WTP_OFF  = 0;         // [24][256][192] bf16 prolog W^T
constexpr size_t WTHH_OFF = 2359296;   // [24][192][64]  bf16 W_hh^T per node
constexpr size_t WTFC_OFF = 2949120;   // [24][64][64]   bf16 W_fc^T per node
constexpr size_t GN_OFF   = 3145728;   // [4][24][24] f32 row-L1-normalized
constexpr size_t BGI_OFF  = 3154944;   // [24][192] f32 folded gi bias
constexpr size_t BHN2_OFF = 3173376;   // [64 j][24 n] f32 b_hh n-slice, n-contig
constexpr size_t BFC2_OFF = 3179520;   // [64 o][24 n] f32 b_fc, n-contig
constexpr size_t TWS_OFF  = 3185664;   // [2048][24][256] bf16 prolog GEMM result
constexpr size_t GIWS_OFF = 28351488;  // [2048][192][24] bf16 gi (n innermost)
constexpr size_t H0WS_OFF = 47225856;  // [2048][24][64] bf16 h0
constexpr size_t WS_NEED  = 53517312;

// t_l (R2-verified): [512 c][8 octet][8 mm] ushort, 64 KB; octets 0-3 used, q=3 zero-pad.
#define BLK(c,q) ((((q) ^ ((c)&3)) | ((((c)>>2)&1)<<2)))
// h_l (ushort index): [n][b][i], b in [0,8), i XOR-swizzled by b and n (R2-verified)
#define HL(n,b,i) ((((n)*8+(b))<<6) + ((i) ^ (((b)&7)<<3) ^ ((((n)>>2)&3)<<4)))

__device__ __forceinline__ float bf2f(ushort u){
  union { uint32_t i; float f; } v; v.i = ((uint32_t)u) << 16; return v.f;
}
__device__ __forceinline__ ushort f2bf(float f){
  union { float f; uint32_t i; } v; v.f = f;
  return (ushort)((v.i + 0x7fffu + ((v.i >> 16) & 1u)) >> 16);
}
__device__ __forceinline__ f32x4 mfma16(bf16x8 a, bf16x8 b, f32x4 c){
  return __builtin_amdgcn_mfma_f32_16x16x32_bf16(a, b, c, 0, 0, 0);
}
__device__ __forceinline__ float sigmoidf_(float x){
  float e = __expf(-x); return __builtin_amdgcn_rcpf(1.f + e);
}
__device__ __forceinline__ float tanhf_(float x){
  float e = __expf(-2.f*fabsf(x));
  float r = (1.f - e)*__builtin_amdgcn_rcpf(1.f + e);
  return copysignf(r, x);
}

// ---------------- G row-normalize ----------------
__global__ void k_gnorm(const float* g0, const float* g1, const float* g2, const float* g3, float* gn){
  int t = threadIdx.x;
  if (t >= 96) return;
  int mat = t / 24, row = t % 24;
  const float* G = (mat==0)? g0 : (mat==1)? g1 : (mat==2)? g2 : g3;
  float s = 0.f;
  for (int m=0;m<24;m++) s += fabsf(G[row*24+m]);
  float inv = 1.f/s;
  for (int m=0;m<24;m++) gn[mat*576 + row*24 + m] = G[row*24+m]*inv;
}

// ---------------- weight transpose/cast + bias prep ----------------
__global__ void k_prep(const float* Wih, const float* Winit, const float* Whh, const float* Wfc,
                       const float* bih, const float* bhh, const float* bfc,
                       ushort* wtp, ushort* wthh, ushort* wtfc, float* bgi,
                       float* bhn2, float* bfc2){
  int stride = gridDim.x*blockDim.x;
  int t0 = blockIdx.x*blockDim.x + threadIdx.x;
  for (int f = t0; f < 884736; f += stride){
    int m = f/36864, rr = f - m*36864, o = rr/192, i = rr - o*192;
    wtp[((size_t)m*256 + o)*192 + i] = f2bf(Wih[(size_t)m*36864 + i*192 + o]);
  }
  for (int f = t0; f < 294912; f += stride){
    int m = f/12288, rr = f - m*12288, o = rr/192, i = rr - o*192;
    wtp[((size_t)m*256 + 192 + o)*192 + i] = f2bf(Winit[(size_t)m*12288 + i*64 + o]);
  }
  for (int f = t0; f < 294912; f += stride){
    int m = f/12288, rr = f - m*12288, o = rr/64, i = rr - o*64;
    wthh[((size_t)m*192 + o)*64 + i] = f2bf(Whh[(size_t)m*12288 + i*192 + o]);
  }
  for (int f = t0; f < 98304; f += stride){
    int m = f/4096, rr = f - m*4096, o = rr/64, i = rr - o*64;
    wtfc[((size_t)m*64 + o)*64 + i] = f2bf(Wfc[(size_t)m*4096 + i*64 + o]);
  }
  for (int f = t0; f < 4608; f += stride){
    int o = f % 192;
    bgi[f] = bih[f] + ((o<128) ? bhh[f] : 0.f);
  }
  for (int f = t0; f < 1536; f += stride){
    int o = f/24, n = f - o*24;
    bhn2[f] = bhh[n*192 + 128 + o];
    bfc2[f] = bfc[n*64 + o];
  }
}

// ---------------- prolog per-node GEMM: rec(64b x 192) @ W^T -> t_ws ----------------
__global__ __launch_bounds__(256) void k_p1(const float* x, const float* h, const ushort* wtp,
                                            ushort* t_ws, int tsel, int o_base, int ntt){
  __shared__ ushort A_lds[64*192];
  int tid = threadIdx.x, w = tid>>6, l = tid&63;
  int m = blockIdx.x, b0 = blockIdx.y*64;
  for (int f = tid; f < 64*192; f += 256){
    int b = f/192, i = f - b*192;
    float v = (i < 64) ? x[((size_t)(b0+b)*3 + tsel)*1536 + m*64 + i]
                       : h[((size_t)(b0+b)*24 + m)*128 + (i-64)];
    A_lds[b*192 + (i ^ ((b&7)<<3))] = f2bf(v);
  }
  __syncthreads();
  for (int mt=0; mt<4; mt++){
    for (int nt = w; nt < ntt; nt += 4){
      f32x4 acc = {0.f,0.f,0.f,0.f};
      int rowb = mt*16 + (l&15);
      int og = o_base + nt*16 + (l&15);
      #pragma unroll
      for (int kc=0;kc<6;kc++){
        int i0 = kc*32 + ((l>>4)<<3);
        bf16x8 av = __builtin_bit_cast(bf16x8, *(const uint4*)(A_lds + rowb*192 + (i0 ^ ((rowb&7)<<3))));
        bf16x8 bv = __builtin_bit_cast(bf16x8, *(const uint4*)(wtp + ((size_t)m*256 + og)*192 + i0));
        acc = mfma16(av, bv, acc);
      }
      #pragma unroll
      for (int r=0;r<4;r++){
        int bp = mt*16 + ((l>>4)<<2) + r;
        t_ws[((size_t)(b0+bp)*24 + m)*256 + og] = f2bf(acc[r]);
      }
    }
  }
}

// ---------------- prolog mix: gi = Gn_ih @ t + bias ; h0 = Gn_init @ t + b_init ----------------
__global__ __launch_bounds__(256) void k_p2(const ushort* t_ws, const float* gn, const float* bgi,
                                            const float* binit, ushort* gi_ws, ushort* h0_ws){
  __shared__ ushort t_l[24*256];
  int tid = threadIdx.x; size_t b = blockIdx.x;
  const uint4* src = (const uint4*)(t_ws + b*6144);
  uint4* dst = (uint4*)t_l;
  for (int f = tid; f < 768; f += 256) dst[f] = src[f];
  __syncthreads();
  int o = tid;
  float acc[24];
  if (o < 192){
    const float* gih = gn + 576;
    #pragma unroll
    for (int n=0;n<24;n++) acc[n] = bgi[n*192+o];
    for (int m=0;m<24;m++){
      float tv = bf2f(t_l[m*256+o]);
      #pragma unroll
      for (int n=0;n<24;n++) acc[n] = fmaf(gih[n*24+m], tv, acc[n]);
    }
    uint ov[12];
    #pragma unroll
    for (int q=0;q<12;q++) ov[q] = (uint)f2bf(acc[2*q]) | ((uint)f2bf(acc[2*q+1])<<16);
    uint4* gdst = (uint4*)(gi_ws + (b*192 + o)*24);
    gdst[0] = make_uint4(ov[0],ov[1],ov[2],ov[3]);
    gdst[1] = make_uint4(ov[4],ov[5],ov[6],ov[7]);
    gdst[2] = make_uint4(ov[8],ov[9],ov[10],ov[11]);
  } else {
    int o2 = o - 192;
    const float* gin = gn;
    #pragma unroll
    for (int n=0;n<24;n++) acc[n] = binit[n*64+o2];
    for (int m=0;m<24;m++){
      float tv = bf2f(t_l[m*256 + 192 + o2]);
      #pragma unroll
      for (int n=0;n<24;n++) acc[n] = fmaf(gin[n*24+m], tv, acc[n]);
    }
    #pragma unroll
    for (int n=0;n<24;n++) h0_ws[(b*24+n)*64 + o2] = f2bf(acc[n]);
  }
}

// ---------------- x_t passthrough (NT stores) ----------------
__global__ void k_copy(const f32x4* x, f32x4* out2){
  int i = blockIdx.x*blockDim.x + threadIdx.x;
  for (; i < 2048*384; i += gridDim.x*blockDim.x){
    int b = i/384; int r = i - b*384;
    f32x4 v = x[(size_t)b*1152 + 768 + r];
    __builtin_nontemporal_store(v, &out2[i]);
  }
}

// ---------------- main GRU loop: 256 blocks x 8-batch tile, 16 waves (4/SIMD) ----------------
__global__ __launch_bounds__(1024,1) void k_main(const ushort* giws, const ushort* h0ws,
    const ushort* wthh, const ushort* wtfc, const float* gn,
    const float* bhn2, const float* bfc2, float* out){
  __shared__ ushort h_l[12288];   // 24n x 8b x 64i, swizzled (24.6 KB)
  __shared__ ushort t_l[32768];   // 512c x 64 (64 KB), BLK octet layout
  __shared__ float bhn_l[1568];   // [o][n], zero-padded tail
  __shared__ float bfc_l[1568];
  const int tid = threadIdx.x, w = tid>>6, l = tid&63;
  const int lr = l&15, lq = l>>4;
  const int b0 = blockIdx.x*8;

  for (int f = tid; f < 1568; f += 1024){
    bhn_l[f] = (f < 1536) ? bhn2[f] : 0.f;
    bfc_l[f] = (f < 1536) ? bfc2[f] : 0.f;
  }
  // zero the q=3 pad octets once
  for (int f = tid; f < 4096; f += 1024){
    int c = f>>3, mm = f&7;
    t_l[(c<<6) + (BLK(c,3)<<3) + mm] = 0;
  }
  // stage h0 -> h_l (swizzled)
  for (int f = tid; f < 3072; f += 1024){
    int idx = f<<2; int b = idx/1536; int r2 = idx - b*1536; int n = r2>>6; int i = r2&63;
    ushort4 v = *(const ushort4*)(h0ws + (size_t)(b0+b)*1536 + r2);
    *(ushort4*)(h_l + HL(n,b,i)) = v;
  }
  // constant Gn A-fragments (rows n, k=m, zero-padded)
  bf16x8 gnhh[2], gnfc[2];
  #pragma unroll
  for (int nt2=0; nt2<2; nt2++){
    union { ushort s[8]; bf16x8 v; } uh, uf;
    int row = nt2*16 + lr;
    #pragma unroll
    for (int jj=0;jj<8;jj++){
      int m = lq*8 + jj;
      bool ok = (row<24) && (m<24);
      uh.s[jj] = ok ? f2bf(gn[2*576 + row*24 + m]) : (ushort)0;
      uf.s[jj] = ok ? f2bf(gn[3*576 + row*24 + m]) : (ushort)0;
    }
    gnhh[nt2] = uh.v; gnfc[nt2] = uf.v;
  }
  // per-task mix coordinates (4 mix tasks/wave) + step-invariant gi fragments in regs
  int cb[4], co[4], cn0[4];
  ushort4 gih0[4], gih1[4], gih2[4];
  #pragma unroll
  for (int k=0;k<4;k++){
    int tId = w + k*16, ct = tId>>1, nt2 = tId&1;
    int c = ct*16 + lr;
    cb[k] = c>>6; co[k] = c&63; cn0[k] = nt2*16 + lq*4;
    size_t base = ((size_t)(b0+cb[k])*192 + co[k])*24 + cn0[k];
    gih0[k] = *(const ushort4*)(giws + base);            // r  (slice 0)
    gih1[k] = *(const ushort4*)(giws + base + 64*24);    // u  (slice 1)
    gih2[k] = *(const ushort4*)(giws + base + 128*24);   // n  (slice 2)
  }
  __syncthreads();

  float g1[4][4];   // r-gate, then nn
  for (int step=0; step<16; step++){
    // phases: p=0 -> r (W cols 0-63), p=1 -> n (cols 128-191), p=2 -> u (cols 64-127)
    #pragma unroll 1
    for (int p=0; p<3; p++){
      const int gs = (p==0) ? 0 : (p==1) ? 2 : 1;
      __syncthreads();
      // per-node t-GEMM (6 tasks/wave), weights from L2
      #pragma unroll
      for (int k=0;k<6;k++){
        int tId = w + k*16, m = tId>>2, nt = tId&3;
        int o_loc = nt*16 + lr;
        const ushort* wb = wthh + (((size_t)m*192 + gs*64 + o_loc)<<6);
        f32x4 acc = {0.f,0.f,0.f,0.f};
        #pragma unroll
        for (int kh=0;kh<2;kh++){
          int i0 = kh*32 + lq*8;
          bf16x8 av = __builtin_bit_cast(bf16x8, *(const uint4*)(h_l + HL(m, lr&7, i0)));
          bf16x8 bv = __builtin_bit_cast(bf16x8, *(const uint4*)(wb + i0));
          acc = mfma16(av, bv, acc);
        }
        if (l < 32){
          #pragma unroll
          for (int r=0;r<4;r++){
            int bp = lq*4 + r, c = (bp<<6) + o_loc;
            t_l[(c<<6) + (BLK(c, m>>3)<<3) + (m&7)] = f2bf(acc[r]);
          }
        }
      }
      __syncthreads();
      // node mix (4 tasks/wave) + gate math
      #pragma unroll
      for (int k=0;k<4;k++){
        int tId = w + k*16, nt2 = tId&1;
        int c = (tId>>1)*16 + lr;
        f32x4 cin;
        if (p==1){
          cin = *(const f32x4*)(bhn_l + co[k]*24 + cn0[k]);
        } else {
          ushort4 gp = (p==0) ? gih0[k] : gih1[k];
          cin[0]=bf2f(gp.x); cin[1]=bf2f(gp.y); cin[2]=bf2f(gp.z); cin[3]=bf2f(gp.w);
        }
        bf16x8 bv = __builtin_bit_cast(bf16x8, *(const uint4*)(t_l + (c<<6) + (BLK(c,lq)<<3)));
        f32x4 fa = mfma16(gnhh[nt2], bv, cin);
        if (p==0){
          #pragma unroll
          for (int r=0;r<4;r++) g1[k][r] = sigmoidf_(fa[r]);
        } else if (p==1){
          ushort4 gp = gih2[k];
          float gin[4] = { bf2f(gp.x), bf2f(gp.y), bf2f(gp.z), bf2f(gp.w) };
          #pragma unroll
          for (int r=0;r<4;r++) g1[k][r] = tanhf_(gin[r] + g1[k][r]*fa[r]);
        } else {
          #pragma unroll
          for (int r=0;r<4;r++){
            int n = cn0[k] + r;
            if (n < 24){
              float ug = sigmoidf_(fa[r]);
              float hp = bf2f(h_l[HL(n, cb[k], co[k])]);
              float hv = (1.f-ug)*g1[k][r] + ug*hp;
              h_l[HL(n, cb[k], co[k])] = f2bf(hv);
            }
          }
        }
      }
    }
    __syncthreads();
    // fc t2-GEMM (6 tasks/wave)
    #pragma unroll
    for (int k=0;k<6;k++){
      int tId = w + k*16, m = tId>>2, nt = tId&3;
      int o_loc = nt*16 + lr;
      const ushort* wb = wtfc + ((((size_t)m<<6) + o_loc)<<6);
      f32x4 acc = {0.f,0.f,0.f,0.f};
      #pragma unroll
      for (int kh=0;kh<2;kh++){
        int i0 = kh*32 + lq*8;
        bf16x8 av = __builtin_bit_cast(bf16x8, *(const uint4*)(h_l + HL(m, lr&7, i0)));
        bf16x8 bv = __builtin_bit_cast(bf16x8, *(const uint4*)(wb + i0));
        acc = mfma16(av, bv, acc);
      }
      if (l < 32){
        #pragma unroll
        for (int r=0;r<4;r++){
          int bp = lq*4 + r, c = (bp<<6) + o_loc;
          t_l[(c<<6) + (BLK(c, m>>3)<<3) + (m&7)] = f2bf(acc[r]);
        }
      }
    }
    __syncthreads();
    // fc mix + tanh + NT store (4 tasks/wave)
    #pragma unroll
    for (int k=0;k<4;k++){
      int tId = w + k*16, nt2 = tId&1;
      int c = (tId>>1)*16 + lr;
      f32x4 cin = *(const f32x4*)(bfc_l + co[k]*24 + cn0[k]);
      bf16x8 bv = __builtin_bit_cast(bf16x8, *(const uint4*)(t_l + (c<<6) + (BLK(c,lq)<<3)));
      f32x4 fa = mfma16(gnfc[nt2], bv, cin);
      #pragma unroll
      for (int r=0;r<4;r++){
        int n = cn0[k] + r;
        if (n < 24){
          float y = tanhf_(fa[r]);
          __builtin_nontemporal_store(y,
            &out[((size_t)(b0+cb[k])*16 + step)*1536 + (n<<6) + co[k]]);
        }
      }
    }
  }
}

extern "C" void kernel_launch(void* const* d_in, const int* in_sizes, int n_in,
                              void* d_out, int out_size, void* d_ws, size_t ws_size,
                              hipStream_t stream){
  if (ws_size < WS_NEED) return;
  const float* x     = (const float*)d_in[0];
  const float* h     = (const float*)d_in[1];
  const float* Winit = (const float*)d_in[4];
  const float* binit = (const float*)d_in[5];
  const float* Ginit = (const float*)d_in[6];
  const float* Wih   = (const float*)d_in[7];
  const float* bih   = (const float*)d_in[8];
  const float* Gih   = (const float*)d_in[9];
  const float* Whh   = (const float*)d_in[10];
  const float* bhh   = (const float*)d_in[11];
  const float* Ghh   = (const float*)d_in[12];
  const float* Wfc   = (const float*)d_in[13];
  const float* bfc   = (const float*)d_in[14];
  const float* Gfc   = (const float*)d_in[15];
  char* ws = (char*)d_ws;
  ushort* wtp  = (ushort*)(ws + WTP_OFF);
  ushort* wthh = (ushort*)(ws + WTHH_OFF);
  ushort* wtfc = (ushort*)(ws + WTFC_OFF);
  float*  gn   = (float*)(ws + GN_OFF);
  float*  bgi  = (float*)(ws + BGI_OFF);
  float*  bhn2 = (float*)(ws + BHN2_OFF);
  float*  bfc2 = (float*)(ws + BFC2_OFF);
  ushort* tws  = (ushort*)(ws + TWS_OFF);
  ushort* giws = (ushort*)(ws + GIWS_OFF);
  ushort* h0ws = (ushort*)(ws + H0WS_OFF);
  float* out  = (float*)d_out;
  float* out2 = out + (size_t)2048*16*1536;

  k_gnorm<<<1, 128, 0, stream>>>(Ginit, Gih, Ghh, Gfc, gn);
  k_prep<<<512, 256, 0, stream>>>(Wih, Winit, Whh, Wfc, bih, bhh, bfc, wtp, wthh, wtfc, bgi, bhn2, bfc2);
  k_p1<<<dim3(24,32), 256, 0, stream>>>(x, h, wtp, tws, 2, 0, 12);
  k_p1<<<dim3(24,32), 256, 0, stream>>>(x, h, wtp, tws, 1, 192, 4);
  k_p2<<<2048, 256, 0, stream>>>(tws, gn, bgi, binit, giws, h0ws);
  k_copy<<<2048, 256, 0, stream>>>((const f32x4*)x, (f32x4*)out2);
  k_main<<<256, 1024, 0, stream>>>(giws, h0ws, wthh, wtfc, gn, bhn2, bfc2, out);
}